// Round 13
// baseline (443.792 us; speedup 1.0000x reference)
//
#include <hip/hip_runtime.h>
#include <hip/hip_fp16.h>

#define NEG_SLOPE 0.2f
#define BKT_BITS 9
#define BKT_NODES 512
#define CHUNK 8192
#define SLICES 8
#define LSL 4                    // lsort slices per bucket

typedef float v4f __attribute__((ext_vector_type(4)));

__device__ __forceinline__ float lrelu(float x) { return x > 0.f ? x : NEG_SLOPE * x; }

// Real hardware LDS float atomic add (emits ds_add_f32)
__device__ __forceinline__ void ldsAddF32(float* p, float v) {
    asm volatile("ds_add_f32 %0, %1" : : "v"((unsigned)(uintptr_t)p), "v"(v));
}

__device__ __forceinline__ int ntLoadI(const int* p) { return __builtin_nontemporal_load(p); }
__device__ __forceinline__ v4f ntLoadV4(const float* p) {
    return __builtin_nontemporal_load((const v4f*)p);
}
__device__ __forceinline__ float ntLoadF(const float* p) { return __builtin_nontemporal_load(p); }
__device__ __forceinline__ void ntStoreF(float* p, float v) { __builtin_nontemporal_store(v, p); }

union H2F { __half2 h; float f; };
__device__ __forceinline__ float2 unpackH2(float bits) {
    H2F u; u.f = bits; return __half22float2(u.h);
}
__device__ __forceinline__ float packH2(float a, float b) {
    H2F u; u.h = __float22half2_rn(make_float2(a, b)); return u.f;
}

// ---------------- Layer-1 init ----------------
__global__ void l1_init_kernel(const float* __restrict__ x,
                               const float* __restrict__ W1,
                               const float* __restrict__ a_s,
                               const float* __restrict__ a_d,
                               float* __restrict__ rec,
                               float* __restrict__ ad_,
                               int N)
{
    __shared__ float Wl[512];
    for (int i = threadIdx.x; i < 512; i += blockDim.x) Wl[i] = W1[i];
    __syncthreads();
    int n = blockIdx.x * blockDim.x + threadIdx.x;
    if (n >= N) return;
    const float* xr = x + (size_t)n * 128;
    float a0 = 0.f, a1 = 0.f, a2 = 0.f, a3 = 0.f;
#pragma unroll 8
    for (int j = 0; j < 32; ++j) {
        v4f v = ntLoadV4(xr + 4 * j);
        const float* w = &Wl[j * 16];
        a0 += v.x * w[0] + v.y * w[4] + v.z * w[8]  + v.w * w[12];
        a1 += v.x * w[1] + v.y * w[5] + v.z * w[9]  + v.w * w[13];
        a2 += v.x * w[2] + v.y * w[6] + v.z * w[10] + v.w * w[14];
        a3 += v.x * w[3] + v.y * w[7] + v.z * w[11] + v.w * w[15];
    }
    float asv = a0 * a_s[0] + a1 * a_s[1] + a2 * a_s[2] + a3 * a_s[3];
    ((float4*)rec)[n] = make_float4(packH2(a0, a1), packH2(a2, a3), asv, 0.f);
    ad_[n] = a0 * a_d[0] + a1 * a_d[1] + a2 * a_d[2] + a3 * a_d[3];
}

// ---------------- pass 1: bucket by dst >> 9 ----------------
__global__ void bhist_kernel(const int* __restrict__ dst, int* __restrict__ bcnt, int E, int nbkt)
{
    __shared__ int h[256];
    h[threadIdx.x] = 0;
    __syncthreads();
    int base = blockIdx.x * CHUNK;
    int end = min(base + CHUNK, E);
    for (int i = base + threadIdx.x; i < end; i += 256)
        atomicAdd(&h[ntLoadI(dst + i) >> BKT_BITS], 1);
    __syncthreads();
    if ((int)threadIdx.x < nbkt && h[threadIdx.x])
        atomicAdd(&bcnt[threadIdx.x], h[threadIdx.x]);
}

__global__ void bscan_kernel(const int* __restrict__ bcnt, int* __restrict__ bo,
                             int* __restrict__ gcur, int nbkt, int E)
{
    __shared__ int sh[256];
    int t = threadIdx.x;
    int v = (t < nbkt) ? bcnt[t] : 0;
    sh[t] = v;
    __syncthreads();
    for (int o = 1; o < 256; o <<= 1) {
        int u = (t >= o) ? sh[t - o] : 0;
        __syncthreads();
        sh[t] += u;
        __syncthreads();
    }
    if (t < nbkt) { int e = sh[t] - v; bo[t] = e; gcur[t] = e; }
    if (t == 0) bo[nbkt] = E;
}

// Direct bucket scatter: per-chunk LDS hist -> global reserve -> plain scattered stores.
// Runs of ~42 contiguous edges per (chunk,bucket) assemble into full lines in L2 write-back.
__global__ void __launch_bounds__(512) bscat_kernel(const int* __restrict__ src,
                                                    const int* __restrict__ dst,
                                                    int* __restrict__ gcur,
                                                    int* __restrict__ packed,
                                                    int E)
{
    __shared__ int hist[256];
    __shared__ int gbase[256];
    __shared__ int lcur[256];
    int t = threadIdx.x;
    if (t < 256) { hist[t] = 0; lcur[t] = 0; }
    __syncthreads();
    int base = blockIdx.x * CHUNK;
    int end = min(base + CHUNK, E);
    for (int i = base + t; i < end; i += 512)
        atomicAdd(&hist[ntLoadI(dst + i) >> BKT_BITS], 1);
    __syncthreads();
    if (t < 256 && hist[t] > 0) gbase[t] = atomicAdd(&gcur[t], hist[t]);
    __syncthreads();
    for (int i = base + t; i < end; i += 512) {
        int d = ntLoadI(dst + i);
        int b = d >> BKT_BITS;
        int r = atomicAdd(&lcur[b], 1);
        packed[gbase[b] + r] = ntLoadI(src + i) | ((d & (BKT_NODES - 1)) << 17);  // plain store
    }
}

// ---------------- pass 1.5: parallel bucket-local exact-dst sort ----------------
// k1: count per (bucket, local dst) with bucket split into LSL slices
__global__ void __launch_bounds__(512) lhist_kernel(const int* __restrict__ bo,
                                                    const int* __restrict__ packed,
                                                    int* __restrict__ cnt)
{
    __shared__ int h[BKT_NODES];
    int b = blockIdx.x / LSL, sl = blockIdx.x % LSL;
    int t = threadIdx.x;
    h[t] = 0;
    __syncthreads();
    int beg = bo[b], end = bo[b + 1];
    int len = end - beg, per = (len + LSL - 1) / LSL;
    int s0 = beg + sl * per, s1 = min(s0 + per, end);
    for (int i = s0 + t; i < s1; i += 512)
        atomicAdd(&h[ntLoadI(packed + i) >> 17], 1);
    __syncthreads();
    if (h[t]) atomicAdd(&cnt[(b << BKT_BITS) + t], h[t]);
}

// k2: per-bucket exclusive scan -> absolute base positions (basecur)
__global__ void __launch_bounds__(512) lscan_kernel(const int* __restrict__ bo,
                                                    const int* __restrict__ cnt,
                                                    int* __restrict__ basecur)
{
    __shared__ int sc[BKT_NODES];
    int b = blockIdx.x, t = threadIdx.x;
    int v = cnt[(b << BKT_BITS) + t];
    sc[t] = v;
    __syncthreads();
    for (int o = 1; o < BKT_NODES; o <<= 1) {
        int u = (t >= o) ? sc[t - o] : 0;
        __syncthreads();
        sc[t] += u;
        __syncthreads();
    }
    basecur[(b << BKT_BITS) + t] = bo[b] + sc[t] - v;
}

// k3: per (bucket,slice): LDS hist -> reserve range from basecur -> scatter (plain stores)
__global__ void __launch_bounds__(512) lscat_kernel(const int* __restrict__ bo,
                                                    const int* __restrict__ packed,
                                                    int* __restrict__ basecur,
                                                    int* __restrict__ packed2)
{
    __shared__ int h[BKT_NODES];
    __shared__ int gb[BKT_NODES];
    __shared__ int lc[BKT_NODES];
    int b = blockIdx.x / LSL, sl = blockIdx.x % LSL;
    int t = threadIdx.x;
    h[t] = 0; lc[t] = 0;
    __syncthreads();
    int beg = bo[b], end = bo[b + 1];
    int len = end - beg, per = (len + LSL - 1) / LSL;
    int s0 = beg + sl * per, s1 = min(s0 + per, end);
    for (int i = s0 + t; i < s1; i += 512)
        atomicAdd(&h[ntLoadI(packed + i) >> 17], 1);
    __syncthreads();
    if (h[t] > 0) gb[t] = atomicAdd(&basecur[(b << BKT_BITS) + t], h[t]);
    __syncthreads();
    for (int i = s0 + t; i < s1; i += 512) {
        int p = ntLoadI(packed + i);
        int ld = p >> 17;
        int r = atomicAdd(&lc[ld], 1);
        packed2[gb[ld] + r] = p;          // plain store -> L2 write-back assembles lines
    }
}

// ---------------- aggregation: register run-accumulation over dst-sorted edges ----------------
template <int F>
__global__ void __launch_bounds__(256) agg4_kernel(const int* __restrict__ bo,
                           const int* __restrict__ packed2,
                           const float* __restrict__ rec, const float* __restrict__ ad_,
                           float* __restrict__ planes, int NP, int N)
{
    constexpr int C = F + 1;
    __shared__ float acc[C * BKT_NODES];
    __shared__ float adl[BKT_NODES];
    int b  = blockIdx.x >> 3;
    int sl = blockIdx.x & 7;
    int t  = threadIdx.x;
    for (int i = t; i < C * BKT_NODES; i += 256) acc[i] = 0.f;
    int nbase = b << BKT_BITS;
    for (int i = t; i < BKT_NODES; i += 256)
        adl[i] = (nbase + i < N) ? ad_[nbase + i] : 0.f;
    __syncthreads();
    int beg = bo[b], end = bo[b + 1];
    int cnt = end - beg;
    int per = (cnt + SLICES - 1) / SLICES;
    int s0 = beg + sl * per;
    int s1 = min(s0 + per, end);
    const v4f* recf = (const v4f*)rec;
    if (s1 > s0) {
        int len = s1 - s0;
        int K = (len + 255) >> 8;          // consecutive edges per thread
        int e0 = s0 + t * K;
        int e1 = min(e0 + K, s1);
        float r0 = 0.f, r1 = 0.f, r2 = 0.f, r3 = 0.f, rw = 0.f, av = 0.f;
        int cur_ld = -1;
        auto flushRun = [&]() {
            if (cur_ld >= 0) {
                ldsAddF32(&acc[0 * BKT_NODES + cur_ld], r0);
                ldsAddF32(&acc[1 * BKT_NODES + cur_ld], r1);
                if (F == 4) {
                    ldsAddF32(&acc[2 * BKT_NODES + cur_ld], r2);
                    ldsAddF32(&acc[3 * BKT_NODES + cur_ld], r3);
                }
                ldsAddF32(&acc[F * BKT_NODES + cur_ld], rw);
            }
        };
        auto consume = [&](int p, v4f q) {
            int ld = p >> 17;
            if (ld != cur_ld) {
                flushRun();
                cur_ld = ld; av = adl[ld];
                r0 = r1 = r2 = r3 = rw = 0.f;
            }
            float w = __expf(lrelu(q.z + av));
            if (F == 4) {
                float2 a01 = unpackH2(q.x), a23 = unpackH2(q.y);
                r0 += w * a01.x; r1 += w * a01.y; r2 += w * a23.x; r3 += w * a23.y;
            } else {
                r0 += w * q.x; r1 += w * q.y;
            }
            rw += w;
        };
        for (int i = e0; i < e1; i += 4) {
            int p0 = packed2[i];
            int p1 = (i + 1 < e1) ? packed2[i + 1] : -1;
            int p2 = (i + 2 < e1) ? packed2[i + 2] : -1;
            int p3 = (i + 3 < e1) ? packed2[i + 3] : -1;
            v4f q0 = recf[p0 & 0x1FFFF];
            v4f q1 = recf[(p1 < 0 ? p0 : p1) & 0x1FFFF];
            v4f q2 = recf[(p2 < 0 ? p0 : p2) & 0x1FFFF];
            v4f q3 = recf[(p3 < 0 ? p0 : p3) & 0x1FFFF];
            consume(p0, q0);
            if (p1 >= 0) consume(p1, q1);
            if (p2 >= 0) consume(p2, q2);
            if (p3 >= 0) consume(p3, q3);
        }
        flushRun();
    }
    asm volatile("s_waitcnt lgkmcnt(0)" ::: "memory");
    __syncthreads();
    float* pl = planes + (size_t)sl * C * NP + nbase;
    for (int i = t; i < C * BKT_NODES; i += 256)
        ntStoreF(&pl[(size_t)(i >> BKT_BITS) * NP + (i & (BKT_NODES - 1))], acc[i]);
}

// ---------------- finalize layers 1,2 ----------------
template <int FO>
__global__ void finA_kernel(const float* __restrict__ planes, int NP,
                            const float* __restrict__ rec, const float* __restrict__ ad_,
                            const float* __restrict__ bias,
                            const float* __restrict__ Wn, const float* __restrict__ ans,
                            const float* __restrict__ andd,
                            float* __restrict__ out_h, float* __restrict__ recn,
                            float* __restrict__ adn_, int N)
{
    int n = blockIdx.x * blockDim.x + threadIdx.x;
    if (n >= N) return;
    float g[5] = {0.f, 0.f, 0.f, 0.f, 0.f};
#pragma unroll
    for (int sl = 0; sl < SLICES; ++sl) {
        const float* pl = planes + (size_t)sl * 5 * NP + n;
#pragma unroll
        for (int c = 0; c < 5; ++c) g[c] += ntLoadF(&pl[(size_t)c * NP]);
    }
    float4 r = ((const float4*)rec)[n];
    float2 h01 = unpackH2(r.x);
    float2 h23 = unpackH2(r.y);
    float w0 = __expf(lrelu(r.z + ad_[n]));
    float inv = 1.f / (g[4] + w0);
    float hr[4];
    hr[0] = tanhf((g[0] + w0 * h01.x) * inv + bias[0]);
    hr[1] = tanhf((g[1] + w0 * h01.y) * inv + bias[1]);
    hr[2] = tanhf((g[2] + w0 * h23.x) * inv + bias[2]);
    hr[3] = tanhf((g[3] + w0 * h23.y) * inv + bias[3]);
    ((float4*)out_h)[n] = make_float4(hr[0], hr[1], hr[2], hr[3]);
    if (FO == 4) {
        float hp[4]; float s = 0.f, d = 0.f;
#pragma unroll
        for (int q = 0; q < 4; ++q) {
            float v = hr[0] * Wn[q] + hr[1] * Wn[4 + q] + hr[2] * Wn[8 + q] + hr[3] * Wn[12 + q];
            hp[q] = v; s += v * ans[q]; d += v * andd[q];
        }
        ((float4*)recn)[n] = make_float4(packH2(hp[0], hp[1]), packH2(hp[2], hp[3]), s, 0.f);
        adn_[n] = d;
    } else {
        float hp0 = hr[0] * Wn[0] + hr[1] * Wn[2] + hr[2] * Wn[4] + hr[3] * Wn[6];
        float hp1 = hr[0] * Wn[1] + hr[1] * Wn[3] + hr[2] * Wn[5] + hr[3] * Wn[7];
        float s = hp0 * ans[0] + hp1 * ans[1];
        ((float4*)recn)[n] = make_float4(hp0, hp1, s, 0.f);
        adn_[n] = hp0 * andd[0] + hp1 * andd[1];
    }
}

// ---------------- finalize layer 3 ----------------
__global__ void finC_kernel(const float* __restrict__ planes, int NP,
                            const float* __restrict__ rec, const float* __restrict__ ad_,
                            const float* __restrict__ bias,
                            const float* __restrict__ Wc, const float* __restrict__ bc,
                            float* __restrict__ out_h, float* __restrict__ out_c, int N)
{
    int n = blockIdx.x * blockDim.x + threadIdx.x;
    if (n >= N) return;
    float g[3] = {0.f, 0.f, 0.f};
#pragma unroll
    for (int sl = 0; sl < SLICES; ++sl) {
        const float* pl = planes + (size_t)sl * 3 * NP + n;
#pragma unroll
        for (int c = 0; c < 3; ++c) g[c] += ntLoadF(&pl[(size_t)c * NP]);
    }
    float4 r = ((const float4*)rec)[n];
    float w0 = __expf(lrelu(r.z + ad_[n]));
    float inv = 1.f / (g[2] + w0);
    float hr0 = tanhf((g[0] + w0 * r.x) * inv + bias[0]);
    float hr1 = tanhf((g[1] + w0 * r.y) * inv + bias[1]);
    ((float2*)out_h)[n] = make_float2(hr0, hr1);
    float o[8];
#pragma unroll
    for (int c = 0; c < 8; ++c) o[c] = hr0 * Wc[c] + hr1 * Wc[8 + c] + bc[c];
    float4* op = (float4*)(out_c + (size_t)n * 8);
    op[0] = make_float4(o[0], o[1], o[2], o[3]);
    op[1] = make_float4(o[4], o[5], o[6], o[7]);
}

extern "C" void kernel_launch(void* const* d_in, const int* in_sizes, int n_in,
                              void* d_out, int out_size, void* d_ws, size_t ws_size,
                              hipStream_t stream)
{
    const float* x   = (const float*)d_in[0];
    const int*   ei  = (const int*)d_in[1];
    const float* W1  = (const float*)d_in[2];
    const float* a1s = (const float*)d_in[3];
    const float* a1d = (const float*)d_in[4];
    const float* b1  = (const float*)d_in[5];
    const float* W2  = (const float*)d_in[6];
    const float* a2s = (const float*)d_in[7];
    const float* a2d = (const float*)d_in[8];
    const float* b2  = (const float*)d_in[9];
    const float* W3  = (const float*)d_in[10];
    const float* a3s = (const float*)d_in[11];
    const float* a3d = (const float*)d_in[12];
    const float* b3  = (const float*)d_in[13];
    const float* Wc  = (const float*)d_in[14];
    const float* bc  = (const float*)d_in[15];

    const int N = in_sizes[0] / 128;
    const int E = in_sizes[1] / 2;
    const int* src = ei;
    const int* dst = ei + E;
    const int nbkt = (N + BKT_NODES - 1) >> BKT_BITS;   // 196
    const int NP = nbkt * BKT_NODES;
    const int nchunks = (E + CHUNK - 1) / CHUNK;

    float* out    = (float*)d_out;
    float* out_h1 = out;
    float* out_h2 = out + (size_t)4 * N;
    float* out_h3 = out + (size_t)8 * N;
    float* out_c  = out + (size_t)10 * N;

    char* ws = (char*)d_ws;
    size_t off = 0;
    auto alloc = [&](size_t bytes) -> void* {
        void* p = ws + off;
        off = (off + bytes + 255) & ~(size_t)255;
        return p;
    };
    int*   bcnt    = (int*)  alloc(256 * 4);
    int*   bo      = (int*)  alloc(257 * 4);
    int*   gcur    = (int*)  alloc(256 * 4);
    int*   cnt     = (int*)  alloc((size_t)NP * 4);
    int*   basecur = (int*)  alloc((size_t)NP * 4);
    int*   packed  = (int*)  alloc((size_t)E * 4);    // dead after lscat -> reused as planes
    int*   packed2 = (int*)  alloc((size_t)E * 4);
    float* recA    = (float*)alloc((size_t)N * 4 * 4);
    float* adA     = (float*)alloc((size_t)N * 4);
    float* recB    = (float*)alloc((size_t)N * 4 * 4);
    float* adB     = (float*)alloc((size_t)N * 4);
    float* planes  = (float*)packed;                  // SLICES*5*NP*4 = 16MB <= 25.6MB
    if (off > ws_size) return;

    const int nb = (N + 255) / 256;

    hipMemsetAsync(bcnt, 0, 256 * 4, stream);
    hipMemsetAsync(cnt, 0, (size_t)NP * 4, stream);
    l1_init_kernel<<<nb, 256, 0, stream>>>(x, W1, a1s, a1d, recA, adA, N);
    // pass 1: bucket-sort by dst>>9 (direct scatter, no LDS staging)
    bhist_kernel<<<nchunks, 256, 0, stream>>>(dst, bcnt, E, nbkt);
    bscan_kernel<<<1, 256, 0, stream>>>(bcnt, bo, gcur, nbkt, E);
    bscat_kernel<<<nchunks, 512, 0, stream>>>(src, dst, gcur, packed, E);
    // pass 1.5: parallel bucket-local exact-dst sort
    lhist_kernel<<<nbkt * LSL, 512, 0, stream>>>(bo, packed, cnt);
    lscan_kernel<<<nbkt, 512, 0, stream>>>(bo, cnt, basecur);
    lscat_kernel<<<nbkt * LSL, 512, 0, stream>>>(bo, packed, basecur, packed2);

    // layer 1
    agg4_kernel<4><<<nbkt * SLICES, 256, 0, stream>>>(bo, packed2, recA, adA, planes, NP, N);
    finA_kernel<4><<<nb, 256, 0, stream>>>(planes, NP, recA, adA, b1, W2, a2s, a2d,
                                           out_h1, recB, adB, N);
    // layer 2
    agg4_kernel<4><<<nbkt * SLICES, 256, 0, stream>>>(bo, packed2, recB, adB, planes, NP, N);
    finA_kernel<2><<<nb, 256, 0, stream>>>(planes, NP, recB, adB, b2, W3, a3s, a3d,
                                           out_h2, recA, adA, N);
    // layer 3
    agg4_kernel<2><<<nbkt * SLICES, 256, 0, stream>>>(bo, packed2, recA, adA, planes, NP, N);
    finC_kernel<<<nb, 256, 0, stream>>>(planes, NP, recA, adA, b3, Wc, bc, out_h3, out_c, N);
}

// Round 14
// 404.768 us; speedup vs baseline: 1.0964x; 1.0964x over previous
//
#include <hip/hip_runtime.h>
#include <hip/hip_fp16.h>

#define NEG_SLOPE 0.2f
#define BKT_BITS 9
#define BKT_NODES 512
#define CHUNK 8192
#define SLICES 8

typedef float v4f __attribute__((ext_vector_type(4)));

__device__ __forceinline__ float lrelu(float x) { return x > 0.f ? x : NEG_SLOPE * x; }

// Real hardware LDS float atomic add (emits ds_add_f32)
__device__ __forceinline__ void ldsAddF32(float* p, float v) {
    asm volatile("ds_add_f32 %0, %1" : : "v"((unsigned)(uintptr_t)p), "v"(v));
}

__device__ __forceinline__ int ntLoadI(const int* p) { return __builtin_nontemporal_load(p); }
__device__ __forceinline__ v4f ntLoadV4(const float* p) {
    return __builtin_nontemporal_load((const v4f*)p);
}
__device__ __forceinline__ float ntLoadF(const float* p) { return __builtin_nontemporal_load(p); }
__device__ __forceinline__ void ntStoreI(int* p, int v) { __builtin_nontemporal_store(v, p); }
__device__ __forceinline__ void ntStoreF(float* p, float v) { __builtin_nontemporal_store(v, p); }

union H2F { __half2 h; float f; };
__device__ __forceinline__ float2 unpackH2(float bits) {
    H2F u; u.f = bits; return __half22float2(u.h);
}
__device__ __forceinline__ float packH2(float a, float b) {
    H2F u; u.h = __float22half2_rn(make_float2(a, b)); return u.f;
}

// ---------------- Layer-1 init ----------------
__global__ void l1_init_kernel(const float* __restrict__ x,
                               const float* __restrict__ W1,
                               const float* __restrict__ a_s,
                               const float* __restrict__ a_d,
                               float* __restrict__ rec,
                               float* __restrict__ ad_,
                               int N)
{
    __shared__ float Wl[512];
    for (int i = threadIdx.x; i < 512; i += blockDim.x) Wl[i] = W1[i];
    __syncthreads();
    int n = blockIdx.x * blockDim.x + threadIdx.x;
    if (n >= N) return;
    const float* xr = x + (size_t)n * 128;
    float a0 = 0.f, a1 = 0.f, a2 = 0.f, a3 = 0.f;
#pragma unroll 8
    for (int j = 0; j < 32; ++j) {
        v4f v = ntLoadV4(xr + 4 * j);
        const float* w = &Wl[j * 16];
        a0 += v.x * w[0] + v.y * w[4] + v.z * w[8]  + v.w * w[12];
        a1 += v.x * w[1] + v.y * w[5] + v.z * w[9]  + v.w * w[13];
        a2 += v.x * w[2] + v.y * w[6] + v.z * w[10] + v.w * w[14];
        a3 += v.x * w[3] + v.y * w[7] + v.z * w[11] + v.w * w[15];
    }
    float asv = a0 * a_s[0] + a1 * a_s[1] + a2 * a_s[2] + a3 * a_s[3];
    ((float4*)rec)[n] = make_float4(packH2(a0, a1), packH2(a2, a3), asv, 0.f);
    ad_[n] = a0 * a_d[0] + a1 * a_d[1] + a2 * a_d[2] + a3 * a_d[3];
}

// ---------------- pass 1: bucket by dst >> 9 ----------------
__global__ void bhist_kernel(const int* __restrict__ dst, int* __restrict__ bcnt, int E, int nbkt)
{
    __shared__ int h[256];
    h[threadIdx.x] = 0;
    __syncthreads();
    int base = blockIdx.x * CHUNK;
    int end = min(base + CHUNK, E);
    for (int i = base + threadIdx.x; i < end; i += 256)
        atomicAdd(&h[ntLoadI(dst + i) >> BKT_BITS], 1);
    __syncthreads();
    if ((int)threadIdx.x < nbkt && h[threadIdx.x])
        atomicAdd(&bcnt[threadIdx.x], h[threadIdx.x]);
}

__global__ void bscan_kernel(const int* __restrict__ bcnt, int* __restrict__ bo,
                             int* __restrict__ gcur, int nbkt, int E)
{
    __shared__ int sh[256];
    int t = threadIdx.x;
    int v = (t < nbkt) ? bcnt[t] : 0;
    sh[t] = v;
    __syncthreads();
    for (int o = 1; o < 256; o <<= 1) {
        int u = (t >= o) ? sh[t - o] : 0;
        __syncthreads();
        sh[t] += u;
        __syncthreads();
    }
    if (t < nbkt) { int e = sh[t] - v; bo[t] = e; gcur[t] = e; }
    if (t == 0) bo[nbkt] = E;
}

// Staged bucket scatter, 512 threads: LDS-stage in bucket order, coalesced nt copy-out
// (single wave writes consecutive addresses -> full lines; avoids cross-XCD partial lines).
__global__ void __launch_bounds__(512) bscat_kernel(const int* __restrict__ src,
                                                    const int* __restrict__ dst,
                                                    int* __restrict__ gcur,
                                                    int* __restrict__ packed,
                                                    int E)
{
    __shared__ int hist[256];
    __shared__ int lbase[256];
    __shared__ int gbase[256];
    __shared__ int lcur[256];
    __shared__ int sc[256];
    __shared__ int stage[CHUNK];
    __shared__ unsigned char sbkt[CHUNK];
    int t = threadIdx.x;
    if (t < 256) { hist[t] = 0; lcur[t] = 0; }
    __syncthreads();
    int base = blockIdx.x * CHUNK;
    int end = min(base + CHUNK, E);
    for (int i = base + t; i < end; i += 512)
        atomicAdd(&hist[ntLoadI(dst + i) >> BKT_BITS], 1);
    __syncthreads();
    int v = (t < 256) ? hist[t] : 0;
    if (t < 256) sc[t] = v;
    __syncthreads();
    for (int o = 1; o < 256; o <<= 1) {
        int u = 0;
        if (t < 256 && t >= o) u = sc[t - o];
        __syncthreads();
        if (t < 256) sc[t] += u;
        __syncthreads();
    }
    if (t < 256) {
        lbase[t] = sc[t] - v;
        if (v > 0) gbase[t] = atomicAdd(&gcur[t], v);
    }
    __syncthreads();
    for (int i = base + t; i < end; i += 512) {
        int d = ntLoadI(dst + i);
        int b = d >> BKT_BITS;
        int r = atomicAdd(&lcur[b], 1);
        int p = lbase[b] + r;
        stage[p] = ntLoadI(src + i) | ((d & (BKT_NODES - 1)) << 17);
        sbkt[p] = (unsigned char)b;
    }
    __syncthreads();
    int cnt = end - base;
    for (int i = t; i < cnt; i += 512) {
        int b = sbkt[i];
        ntStoreI(&packed[gbase[b] + (i - lbase[b])], stage[i]);
    }
}

// ---------------- pass 1.5: bucket-local exact-dst sort, dst-range-split x2 ----------------
// Each block: full hist+scan of its bucket, but scatters only its dst-half.
// Blocks own DISJOINT output ranges -> no cross-XCD partial-line sharing; plain stores
// assemble in the owning L2 (nt write-through here cost 3x write-amp in R10).
__global__ void __launch_bounds__(1024) lsort_kernel(const int* __restrict__ bo,
                                                     const int* __restrict__ packed,
                                                     int* __restrict__ packed2)
{
    __shared__ int hist[BKT_NODES];
    __shared__ int sc[BKT_NODES];
    __shared__ int lcur[BKT_NODES];
    int b = blockIdx.x >> 1, half = blockIdx.x & 1;
    int t = threadIdx.x;
    int beg = bo[b], end = bo[b + 1];
    if (t < BKT_NODES) hist[t] = 0;
    __syncthreads();
    for (int i = beg + t; i < end; i += 1024)
        atomicAdd(&hist[ntLoadI(packed + i) >> 17], 1);
    __syncthreads();
    if (t < BKT_NODES) sc[t] = hist[t];
    __syncthreads();
    for (int o = 1; o < BKT_NODES; o <<= 1) {
        int u = 0;
        if (t < BKT_NODES && t >= o) u = sc[t - o];
        __syncthreads();
        if (t < BKT_NODES) sc[t] += u;
        __syncthreads();
    }
    if (t < BKT_NODES) lcur[t] = beg + sc[t] - hist[t];   // exclusive base for local dst t
    __syncthreads();
    for (int i = beg + t; i < end; i += 1024) {
        int p = ntLoadI(packed + i);
        int ld = p >> 17;
        if ((ld >> 8) == half) {                           // scatter only our dst-half
            int pos = atomicAdd(&lcur[ld], 1);
            packed2[pos] = p;                              // plain store -> L2 write-back
        }
    }
}

// ---------------- aggregation: register run-accumulation over dst-sorted edges ----------------
template <int F>
__global__ void __launch_bounds__(256) agg4_kernel(const int* __restrict__ bo,
                           const int* __restrict__ packed2,
                           const float* __restrict__ rec, const float* __restrict__ ad_,
                           float* __restrict__ planes, int NP, int N)
{
    constexpr int C = F + 1;
    __shared__ float acc[C * BKT_NODES];
    __shared__ float adl[BKT_NODES];
    int b  = blockIdx.x >> 3;
    int sl = blockIdx.x & 7;
    int t  = threadIdx.x;
    for (int i = t; i < C * BKT_NODES; i += 256) acc[i] = 0.f;
    int nbase = b << BKT_BITS;
    for (int i = t; i < BKT_NODES; i += 256)
        adl[i] = (nbase + i < N) ? ad_[nbase + i] : 0.f;
    __syncthreads();
    int beg = bo[b], end = bo[b + 1];
    int cnt = end - beg;
    int per = (cnt + SLICES - 1) / SLICES;
    int s0 = beg + sl * per;
    int s1 = min(s0 + per, end);
    const v4f* recf = (const v4f*)rec;
    if (s1 > s0) {
        int len = s1 - s0;
        int K = (len + 255) >> 8;          // consecutive edges per thread
        int e0 = s0 + t * K;
        int e1 = min(e0 + K, s1);
        float r0 = 0.f, r1 = 0.f, r2 = 0.f, r3 = 0.f, rw = 0.f, av = 0.f;
        int cur_ld = -1;
        auto flushRun = [&]() {
            if (cur_ld >= 0) {
                ldsAddF32(&acc[0 * BKT_NODES + cur_ld], r0);
                ldsAddF32(&acc[1 * BKT_NODES + cur_ld], r1);
                if (F == 4) {
                    ldsAddF32(&acc[2 * BKT_NODES + cur_ld], r2);
                    ldsAddF32(&acc[3 * BKT_NODES + cur_ld], r3);
                }
                ldsAddF32(&acc[F * BKT_NODES + cur_ld], rw);
            }
        };
        auto consume = [&](int p, v4f q) {
            int ld = p >> 17;
            if (ld != cur_ld) {
                flushRun();
                cur_ld = ld; av = adl[ld];
                r0 = r1 = r2 = r3 = rw = 0.f;
            }
            float w = __expf(lrelu(q.z + av));
            if (F == 4) {
                float2 a01 = unpackH2(q.x), a23 = unpackH2(q.y);
                r0 += w * a01.x; r1 += w * a01.y; r2 += w * a23.x; r3 += w * a23.y;
            } else {
                r0 += w * q.x; r1 += w * q.y;
            }
            rw += w;
        };
        for (int i = e0; i < e1; i += 4) {
            int p0 = packed2[i];
            int p1 = (i + 1 < e1) ? packed2[i + 1] : -1;
            int p2 = (i + 2 < e1) ? packed2[i + 2] : -1;
            int p3 = (i + 3 < e1) ? packed2[i + 3] : -1;
            v4f q0 = recf[p0 & 0x1FFFF];
            v4f q1 = recf[(p1 < 0 ? p0 : p1) & 0x1FFFF];
            v4f q2 = recf[(p2 < 0 ? p0 : p2) & 0x1FFFF];
            v4f q3 = recf[(p3 < 0 ? p0 : p3) & 0x1FFFF];
            consume(p0, q0);
            if (p1 >= 0) consume(p1, q1);
            if (p2 >= 0) consume(p2, q2);
            if (p3 >= 0) consume(p3, q3);
        }
        flushRun();
    }
    asm volatile("s_waitcnt lgkmcnt(0)" ::: "memory");
    __syncthreads();
    float* pl = planes + (size_t)sl * C * NP + nbase;
    for (int i = t; i < C * BKT_NODES; i += 256)
        ntStoreF(&pl[(size_t)(i >> BKT_BITS) * NP + (i & (BKT_NODES - 1))], acc[i]);
}

// ---------------- finalize layers 1,2 ----------------
template <int FO>
__global__ void finA_kernel(const float* __restrict__ planes, int NP,
                            const float* __restrict__ rec, const float* __restrict__ ad_,
                            const float* __restrict__ bias,
                            const float* __restrict__ Wn, const float* __restrict__ ans,
                            const float* __restrict__ andd,
                            float* __restrict__ out_h, float* __restrict__ recn,
                            float* __restrict__ adn_, int N)
{
    int n = blockIdx.x * blockDim.x + threadIdx.x;
    if (n >= N) return;
    float g[5] = {0.f, 0.f, 0.f, 0.f, 0.f};
#pragma unroll
    for (int sl = 0; sl < SLICES; ++sl) {
        const float* pl = planes + (size_t)sl * 5 * NP + n;
#pragma unroll
        for (int c = 0; c < 5; ++c) g[c] += ntLoadF(&pl[(size_t)c * NP]);
    }
    float4 r = ((const float4*)rec)[n];
    float2 h01 = unpackH2(r.x);
    float2 h23 = unpackH2(r.y);
    float w0 = __expf(lrelu(r.z + ad_[n]));
    float inv = 1.f / (g[4] + w0);
    float hr[4];
    hr[0] = tanhf((g[0] + w0 * h01.x) * inv + bias[0]);
    hr[1] = tanhf((g[1] + w0 * h01.y) * inv + bias[1]);
    hr[2] = tanhf((g[2] + w0 * h23.x) * inv + bias[2]);
    hr[3] = tanhf((g[3] + w0 * h23.y) * inv + bias[3]);
    ((float4*)out_h)[n] = make_float4(hr[0], hr[1], hr[2], hr[3]);
    if (FO == 4) {
        float hp[4]; float s = 0.f, d = 0.f;
#pragma unroll
        for (int q = 0; q < 4; ++q) {
            float v = hr[0] * Wn[q] + hr[1] * Wn[4 + q] + hr[2] * Wn[8 + q] + hr[3] * Wn[12 + q];
            hp[q] = v; s += v * ans[q]; d += v * andd[q];
        }
        ((float4*)recn)[n] = make_float4(packH2(hp[0], hp[1]), packH2(hp[2], hp[3]), s, 0.f);
        adn_[n] = d;
    } else {
        float hp0 = hr[0] * Wn[0] + hr[1] * Wn[2] + hr[2] * Wn[4] + hr[3] * Wn[6];
        float hp1 = hr[0] * Wn[1] + hr[1] * Wn[3] + hr[2] * Wn[5] + hr[3] * Wn[7];
        float s = hp0 * ans[0] + hp1 * ans[1];
        ((float4*)recn)[n] = make_float4(hp0, hp1, s, 0.f);
        adn_[n] = hp0 * andd[0] + hp1 * andd[1];
    }
}

// ---------------- finalize layer 3 ----------------
__global__ void finC_kernel(const float* __restrict__ planes, int NP,
                            const float* __restrict__ rec, const float* __restrict__ ad_,
                            const float* __restrict__ bias,
                            const float* __restrict__ Wc, const float* __restrict__ bc,
                            float* __restrict__ out_h, float* __restrict__ out_c, int N)
{
    int n = blockIdx.x * blockDim.x + threadIdx.x;
    if (n >= N) return;
    float g[3] = {0.f, 0.f, 0.f};
#pragma unroll
    for (int sl = 0; sl < SLICES; ++sl) {
        const float* pl = planes + (size_t)sl * 3 * NP + n;
#pragma unroll
        for (int c = 0; c < 3; ++c) g[c] += ntLoadF(&pl[(size_t)c * NP]);
    }
    float4 r = ((const float4*)rec)[n];
    float w0 = __expf(lrelu(r.z + ad_[n]));
    float inv = 1.f / (g[2] + w0);
    float hr0 = tanhf((g[0] + w0 * r.x) * inv + bias[0]);
    float hr1 = tanhf((g[1] + w0 * r.y) * inv + bias[1]);
    ((float2*)out_h)[n] = make_float2(hr0, hr1);
    float o[8];
#pragma unroll
    for (int c = 0; c < 8; ++c) o[c] = hr0 * Wc[c] + hr1 * Wc[8 + c] + bc[c];
    float4* op = (float4*)(out_c + (size_t)n * 8);
    op[0] = make_float4(o[0], o[1], o[2], o[3]);
    op[1] = make_float4(o[4], o[5], o[6], o[7]);
}

extern "C" void kernel_launch(void* const* d_in, const int* in_sizes, int n_in,
                              void* d_out, int out_size, void* d_ws, size_t ws_size,
                              hipStream_t stream)
{
    const float* x   = (const float*)d_in[0];
    const int*   ei  = (const int*)d_in[1];
    const float* W1  = (const float*)d_in[2];
    const float* a1s = (const float*)d_in[3];
    const float* a1d = (const float*)d_in[4];
    const float* b1  = (const float*)d_in[5];
    const float* W2  = (const float*)d_in[6];
    const float* a2s = (const float*)d_in[7];
    const float* a2d = (const float*)d_in[8];
    const float* b2  = (const float*)d_in[9];
    const float* W3  = (const float*)d_in[10];
    const float* a3s = (const float*)d_in[11];
    const float* a3d = (const float*)d_in[12];
    const float* b3  = (const float*)d_in[13];
    const float* Wc  = (const float*)d_in[14];
    const float* bc  = (const float*)d_in[15];

    const int N = in_sizes[0] / 128;
    const int E = in_sizes[1] / 2;
    const int* src = ei;
    const int* dst = ei + E;
    const int nbkt = (N + BKT_NODES - 1) >> BKT_BITS;   // 196
    const int NP = nbkt * BKT_NODES;
    const int nchunks = (E + CHUNK - 1) / CHUNK;

    float* out    = (float*)d_out;
    float* out_h1 = out;
    float* out_h2 = out + (size_t)4 * N;
    float* out_h3 = out + (size_t)8 * N;
    float* out_c  = out + (size_t)10 * N;

    char* ws = (char*)d_ws;
    size_t off = 0;
    auto alloc = [&](size_t bytes) -> void* {
        void* p = ws + off;
        off = (off + bytes + 255) & ~(size_t)255;
        return p;
    };
    int*   bcnt    = (int*)  alloc(256 * 4);
    int*   bo      = (int*)  alloc(257 * 4);
    int*   gcur    = (int*)  alloc(256 * 4);
    int*   packed  = (int*)  alloc((size_t)E * 4);    // dead after lsort -> reused as planes
    int*   packed2 = (int*)  alloc((size_t)E * 4);
    float* recA    = (float*)alloc((size_t)N * 4 * 4);
    float* adA     = (float*)alloc((size_t)N * 4);
    float* recB    = (float*)alloc((size_t)N * 4 * 4);
    float* adB     = (float*)alloc((size_t)N * 4);
    float* planes  = (float*)packed;                  // SLICES*5*NP*4 = 16MB <= 25.6MB
    if (off > ws_size) return;

    const int nb = (N + 255) / 256;

    hipMemsetAsync(bcnt, 0, 256 * 4, stream);
    l1_init_kernel<<<nb, 256, 0, stream>>>(x, W1, a1s, a1d, recA, adA, N);
    // pass 1: bucket-sort by dst>>9 (staged, coalesced copy-out)
    bhist_kernel<<<nchunks, 256, 0, stream>>>(dst, bcnt, E, nbkt);
    bscan_kernel<<<1, 256, 0, stream>>>(bcnt, bo, gcur, nbkt, E);
    bscat_kernel<<<nchunks, 512, 0, stream>>>(src, dst, gcur, packed, E);
    // pass 1.5: bucket-local exact-dst sort, dst-range-split x2
    lsort_kernel<<<nbkt * 2, 1024, 0, stream>>>(bo, packed, packed2);

    // layer 1
    agg4_kernel<4><<<nbkt * SLICES, 256, 0, stream>>>(bo, packed2, recA, adA, planes, NP, N);
    finA_kernel<4><<<nb, 256, 0, stream>>>(planes, NP, recA, adA, b1, W2, a2s, a2d,
                                           out_h1, recB, adB, N);
    // layer 2
    agg4_kernel<4><<<nbkt * SLICES, 256, 0, stream>>>(bo, packed2, recB, adB, planes, NP, N);
    finA_kernel<2><<<nb, 256, 0, stream>>>(planes, NP, recB, adB, b2, W3, a3s, a3d,
                                           out_h2, recA, adA, N);
    // layer 3
    agg4_kernel<2><<<nbkt * SLICES, 256, 0, stream>>>(bo, packed2, recA, adA, planes, NP, N);
    finC_kernel<<<nb, 256, 0, stream>>>(planes, NP, recA, adA, b3, Wc, bc, out_h3, out_c, N);
}

// Round 15
// 397.460 us; speedup vs baseline: 1.1166x; 1.0184x over previous
//
#include <hip/hip_runtime.h>
#include <hip/hip_fp16.h>

#define NEG_SLOPE 0.2f
#define BKT_BITS 9
#define BKT_NODES 512
#define CHUNK 8192
#define SLICES 8

typedef float v4f __attribute__((ext_vector_type(4)));

__device__ __forceinline__ float lrelu(float x) { return x > 0.f ? x : NEG_SLOPE * x; }

// Real hardware LDS float atomic add (emits ds_add_f32)
__device__ __forceinline__ void ldsAddF32(float* p, float v) {
    asm volatile("ds_add_f32 %0, %1" : : "v"((unsigned)(uintptr_t)p), "v"(v));
}

__device__ __forceinline__ int ntLoadI(const int* p) { return __builtin_nontemporal_load(p); }
__device__ __forceinline__ v4f ntLoadV4(const float* p) {
    return __builtin_nontemporal_load((const v4f*)p);
}
__device__ __forceinline__ float ntLoadF(const float* p) { return __builtin_nontemporal_load(p); }
__device__ __forceinline__ void ntStoreI(int* p, int v) { __builtin_nontemporal_store(v, p); }
__device__ __forceinline__ void ntStoreF(float* p, float v) { __builtin_nontemporal_store(v, p); }

union H2F { __half2 h; float f; };
__device__ __forceinline__ float2 unpackH2(float bits) {
    H2F u; u.f = bits; return __half22float2(u.h);
}
__device__ __forceinline__ float packH2(float a, float b) {
    H2F u; u.h = __float22half2_rn(make_float2(a, b)); return u.f;
}

// ---------------- Layer-1 init ----------------
__global__ void l1_init_kernel(const float* __restrict__ x,
                               const float* __restrict__ W1,
                               const float* __restrict__ a_s,
                               const float* __restrict__ a_d,
                               float* __restrict__ rec,
                               float* __restrict__ ad_,
                               int N)
{
    __shared__ float Wl[512];
    for (int i = threadIdx.x; i < 512; i += blockDim.x) Wl[i] = W1[i];
    __syncthreads();
    int n = blockIdx.x * blockDim.x + threadIdx.x;
    if (n >= N) return;
    const float* xr = x + (size_t)n * 128;
    float a0 = 0.f, a1 = 0.f, a2 = 0.f, a3 = 0.f;
#pragma unroll 8
    for (int j = 0; j < 32; ++j) {
        v4f v = ntLoadV4(xr + 4 * j);
        const float* w = &Wl[j * 16];
        a0 += v.x * w[0] + v.y * w[4] + v.z * w[8]  + v.w * w[12];
        a1 += v.x * w[1] + v.y * w[5] + v.z * w[9]  + v.w * w[13];
        a2 += v.x * w[2] + v.y * w[6] + v.z * w[10] + v.w * w[14];
        a3 += v.x * w[3] + v.y * w[7] + v.z * w[11] + v.w * w[15];
    }
    float asv = a0 * a_s[0] + a1 * a_s[1] + a2 * a_s[2] + a3 * a_s[3];
    ((float4*)rec)[n] = make_float4(packH2(a0, a1), packH2(a2, a3), asv, 0.f);
    ad_[n] = a0 * a_d[0] + a1 * a_d[1] + a2 * a_d[2] + a3 * a_d[3];
}

// ---------------- pass 1: bucket by dst >> 9 ----------------
__global__ void bhist_kernel(const int* __restrict__ dst, int* __restrict__ bcnt, int E, int nbkt)
{
    __shared__ int h[256];
    h[threadIdx.x] = 0;
    __syncthreads();
    int base = blockIdx.x * CHUNK;
    int end = min(base + CHUNK, E);
    for (int i = base + threadIdx.x; i < end; i += 256)
        atomicAdd(&h[ntLoadI(dst + i) >> BKT_BITS], 1);
    __syncthreads();
    if ((int)threadIdx.x < nbkt && h[threadIdx.x])
        atomicAdd(&bcnt[threadIdx.x], h[threadIdx.x]);
}

__global__ void bscan_kernel(const int* __restrict__ bcnt, int* __restrict__ bo,
                             int* __restrict__ gcur, int nbkt, int E)
{
    __shared__ int sh[256];
    int t = threadIdx.x;
    int v = (t < nbkt) ? bcnt[t] : 0;
    sh[t] = v;
    __syncthreads();
    for (int o = 1; o < 256; o <<= 1) {
        int u = (t >= o) ? sh[t - o] : 0;
        __syncthreads();
        sh[t] += u;
        __syncthreads();
    }
    if (t < nbkt) { int e = sh[t] - v; bo[t] = e; gcur[t] = e; }
    if (t == 0) bo[nbkt] = E;
}

// Staged bucket scatter, 512 threads: LDS-stage in bucket order, coalesced nt copy-out
// (single wave writes consecutive addresses -> full lines; avoids cross-XCD partial lines).
__global__ void __launch_bounds__(512) bscat_kernel(const int* __restrict__ src,
                                                    const int* __restrict__ dst,
                                                    int* __restrict__ gcur,
                                                    int* __restrict__ packed,
                                                    int E)
{
    __shared__ int hist[256];
    __shared__ int lbase[256];
    __shared__ int gbase[256];
    __shared__ int lcur[256];
    __shared__ int sc[256];
    __shared__ int stage[CHUNK];
    __shared__ unsigned char sbkt[CHUNK];
    int t = threadIdx.x;
    if (t < 256) { hist[t] = 0; lcur[t] = 0; }
    __syncthreads();
    int base = blockIdx.x * CHUNK;
    int end = min(base + CHUNK, E);
    for (int i = base + t; i < end; i += 512)
        atomicAdd(&hist[ntLoadI(dst + i) >> BKT_BITS], 1);
    __syncthreads();
    int v = (t < 256) ? hist[t] : 0;
    if (t < 256) sc[t] = v;
    __syncthreads();
    for (int o = 1; o < 256; o <<= 1) {
        int u = 0;
        if (t < 256 && t >= o) u = sc[t - o];
        __syncthreads();
        if (t < 256) sc[t] += u;
        __syncthreads();
    }
    if (t < 256) {
        lbase[t] = sc[t] - v;
        if (v > 0) gbase[t] = atomicAdd(&gcur[t], v);
    }
    __syncthreads();
    for (int i = base + t; i < end; i += 512) {
        int d = ntLoadI(dst + i);
        int b = d >> BKT_BITS;
        int r = atomicAdd(&lcur[b], 1);
        int p = lbase[b] + r;
        stage[p] = ntLoadI(src + i) | ((d & (BKT_NODES - 1)) << 17);
        sbkt[p] = (unsigned char)b;
    }
    __syncthreads();
    int cnt = end - base;
    for (int i = t; i < cnt; i += 512) {
        int b = sbkt[i];
        ntStoreI(&packed[gbase[b] + (i - lbase[b])], stage[i]);
    }
}

// ---------------- pass 1.5: bucket-local exact-dst sort (single block owns bucket) ----------------
// One block sorts one bucket; its scattered plain stores stay within the bucket's own
// ~131KB span -> lines assemble in the owning XCD's L2 and evict once. (Proven best in R11;
// nt stores = 3x write-amp (R10), dst-split x2 = redundant reads + worse amp (R13).)
__global__ void __launch_bounds__(1024) lsort_kernel(const int* __restrict__ bo,
                                                     const int* __restrict__ packed,
                                                     int* __restrict__ packed2)
{
    __shared__ int hist[BKT_NODES];
    __shared__ int sc[BKT_NODES];
    __shared__ int lcur[BKT_NODES];
    int b = blockIdx.x, t = threadIdx.x;
    int beg = bo[b], end = bo[b + 1];
    if (t < BKT_NODES) hist[t] = 0;
    __syncthreads();
    for (int i = beg + t; i < end; i += 1024)
        atomicAdd(&hist[ntLoadI(packed + i) >> 17], 1);
    __syncthreads();
    if (t < BKT_NODES) sc[t] = hist[t];
    __syncthreads();
    for (int o = 1; o < BKT_NODES; o <<= 1) {
        int u = 0;
        if (t < BKT_NODES && t >= o) u = sc[t - o];
        __syncthreads();
        if (t < BKT_NODES) sc[t] += u;
        __syncthreads();
    }
    if (t < BKT_NODES) lcur[t] = beg + sc[t] - hist[t];   // exclusive base for local dst t
    __syncthreads();
    for (int i = beg + t; i < end; i += 1024) {
        int p = ntLoadI(packed + i);
        int pos = atomicAdd(&lcur[p >> 17], 1);
        packed2[pos] = p;                                  // plain store -> L2 write-back
    }
}

// ---------------- aggregation: register run-accumulation over dst-sorted edges ----------------
template <int F>
__global__ void __launch_bounds__(256) agg4_kernel(const int* __restrict__ bo,
                           const int* __restrict__ packed2,
                           const float* __restrict__ rec, const float* __restrict__ ad_,
                           float* __restrict__ planes, int NP, int N)
{
    constexpr int C = F + 1;
    __shared__ float acc[C * BKT_NODES];
    __shared__ float adl[BKT_NODES];
    int b  = blockIdx.x >> 3;
    int sl = blockIdx.x & 7;
    int t  = threadIdx.x;
    for (int i = t; i < C * BKT_NODES; i += 256) acc[i] = 0.f;
    int nbase = b << BKT_BITS;
    for (int i = t; i < BKT_NODES; i += 256)
        adl[i] = (nbase + i < N) ? ad_[nbase + i] : 0.f;
    __syncthreads();
    int beg = bo[b], end = bo[b + 1];
    int cnt = end - beg;
    int per = (cnt + SLICES - 1) / SLICES;
    int s0 = beg + sl * per;
    int s1 = min(s0 + per, end);
    const v4f* recf = (const v4f*)rec;
    if (s1 > s0) {
        int len = s1 - s0;
        int K = (len + 255) >> 8;          // consecutive edges per thread
        int e0 = s0 + t * K;
        int e1 = min(e0 + K, s1);
        float r0 = 0.f, r1 = 0.f, r2 = 0.f, r3 = 0.f, rw = 0.f, av = 0.f;
        int cur_ld = -1;
        auto flushRun = [&]() {
            if (cur_ld >= 0) {
                ldsAddF32(&acc[0 * BKT_NODES + cur_ld], r0);
                ldsAddF32(&acc[1 * BKT_NODES + cur_ld], r1);
                if (F == 4) {
                    ldsAddF32(&acc[2 * BKT_NODES + cur_ld], r2);
                    ldsAddF32(&acc[3 * BKT_NODES + cur_ld], r3);
                }
                ldsAddF32(&acc[F * BKT_NODES + cur_ld], rw);
            }
        };
        auto consume = [&](int p, v4f q) {
            int ld = p >> 17;
            if (ld != cur_ld) {
                flushRun();
                cur_ld = ld; av = adl[ld];
                r0 = r1 = r2 = r3 = rw = 0.f;
            }
            float w = __expf(lrelu(q.z + av));
            if (F == 4) {
                float2 a01 = unpackH2(q.x), a23 = unpackH2(q.y);
                r0 += w * a01.x; r1 += w * a01.y; r2 += w * a23.x; r3 += w * a23.y;
            } else {
                r0 += w * q.x; r1 += w * q.y;
            }
            rw += w;
        };
        for (int i = e0; i < e1; i += 4) {
            int p0 = packed2[i];
            int p1 = (i + 1 < e1) ? packed2[i + 1] : -1;
            int p2 = (i + 2 < e1) ? packed2[i + 2] : -1;
            int p3 = (i + 3 < e1) ? packed2[i + 3] : -1;
            v4f q0 = recf[p0 & 0x1FFFF];
            v4f q1 = recf[(p1 < 0 ? p0 : p1) & 0x1FFFF];
            v4f q2 = recf[(p2 < 0 ? p0 : p2) & 0x1FFFF];
            v4f q3 = recf[(p3 < 0 ? p0 : p3) & 0x1FFFF];
            consume(p0, q0);
            if (p1 >= 0) consume(p1, q1);
            if (p2 >= 0) consume(p2, q2);
            if (p3 >= 0) consume(p3, q3);
        }
        flushRun();
    }
    asm volatile("s_waitcnt lgkmcnt(0)" ::: "memory");
    __syncthreads();
    float* pl = planes + (size_t)sl * C * NP + nbase;
    for (int i = t; i < C * BKT_NODES; i += 256)
        ntStoreF(&pl[(size_t)(i >> BKT_BITS) * NP + (i & (BKT_NODES - 1))], acc[i]);
}

// ---------------- finalize layers 1,2 ----------------
template <int FO>
__global__ void finA_kernel(const float* __restrict__ planes, int NP,
                            const float* __restrict__ rec, const float* __restrict__ ad_,
                            const float* __restrict__ bias,
                            const float* __restrict__ Wn, const float* __restrict__ ans,
                            const float* __restrict__ andd,
                            float* __restrict__ out_h, float* __restrict__ recn,
                            float* __restrict__ adn_, int N)
{
    int n = blockIdx.x * blockDim.x + threadIdx.x;
    if (n >= N) return;
    float g[5] = {0.f, 0.f, 0.f, 0.f, 0.f};
#pragma unroll
    for (int sl = 0; sl < SLICES; ++sl) {
        const float* pl = planes + (size_t)sl * 5 * NP + n;
#pragma unroll
        for (int c = 0; c < 5; ++c) g[c] += ntLoadF(&pl[(size_t)c * NP]);
    }
    float4 r = ((const float4*)rec)[n];
    float2 h01 = unpackH2(r.x);
    float2 h23 = unpackH2(r.y);
    float w0 = __expf(lrelu(r.z + ad_[n]));
    float inv = 1.f / (g[4] + w0);
    float hr[4];
    hr[0] = tanhf((g[0] + w0 * h01.x) * inv + bias[0]);
    hr[1] = tanhf((g[1] + w0 * h01.y) * inv + bias[1]);
    hr[2] = tanhf((g[2] + w0 * h23.x) * inv + bias[2]);
    hr[3] = tanhf((g[3] + w0 * h23.y) * inv + bias[3]);
    ((float4*)out_h)[n] = make_float4(hr[0], hr[1], hr[2], hr[3]);
    if (FO == 4) {
        float hp[4]; float s = 0.f, d = 0.f;
#pragma unroll
        for (int q = 0; q < 4; ++q) {
            float v = hr[0] * Wn[q] + hr[1] * Wn[4 + q] + hr[2] * Wn[8 + q] + hr[3] * Wn[12 + q];
            hp[q] = v; s += v * ans[q]; d += v * andd[q];
        }
        ((float4*)recn)[n] = make_float4(packH2(hp[0], hp[1]), packH2(hp[2], hp[3]), s, 0.f);
        adn_[n] = d;
    } else {
        float hp0 = hr[0] * Wn[0] + hr[1] * Wn[2] + hr[2] * Wn[4] + hr[3] * Wn[6];
        float hp1 = hr[0] * Wn[1] + hr[1] * Wn[3] + hr[2] * Wn[5] + hr[3] * Wn[7];
        float s = hp0 * ans[0] + hp1 * ans[1];
        ((float4*)recn)[n] = make_float4(hp0, hp1, s, 0.f);
        adn_[n] = hp0 * andd[0] + hp1 * andd[1];
    }
}

// ---------------- finalize layer 3 ----------------
__global__ void finC_kernel(const float* __restrict__ planes, int NP,
                            const float* __restrict__ rec, const float* __restrict__ ad_,
                            const float* __restrict__ bias,
                            const float* __restrict__ Wc, const float* __restrict__ bc,
                            float* __restrict__ out_h, float* __restrict__ out_c, int N)
{
    int n = blockIdx.x * blockDim.x + threadIdx.x;
    if (n >= N) return;
    float g[3] = {0.f, 0.f, 0.f};
#pragma unroll
    for (int sl = 0; sl < SLICES; ++sl) {
        const float* pl = planes + (size_t)sl * 3 * NP + n;
#pragma unroll
        for (int c = 0; c < 3; ++c) g[c] += ntLoadF(&pl[(size_t)c * NP]);
    }
    float4 r = ((const float4*)rec)[n];
    float w0 = __expf(lrelu(r.z + ad_[n]));
    float inv = 1.f / (g[2] + w0);
    float hr0 = tanhf((g[0] + w0 * r.x) * inv + bias[0]);
    float hr1 = tanhf((g[1] + w0 * r.y) * inv + bias[1]);
    ((float2*)out_h)[n] = make_float2(hr0, hr1);
    float o[8];
#pragma unroll
    for (int c = 0; c < 8; ++c) o[c] = hr0 * Wc[c] + hr1 * Wc[8 + c] + bc[c];
    float4* op = (float4*)(out_c + (size_t)n * 8);
    op[0] = make_float4(o[0], o[1], o[2], o[3]);
    op[1] = make_float4(o[4], o[5], o[6], o[7]);
}

extern "C" void kernel_launch(void* const* d_in, const int* in_sizes, int n_in,
                              void* d_out, int out_size, void* d_ws, size_t ws_size,
                              hipStream_t stream)
{
    const float* x   = (const float*)d_in[0];
    const int*   ei  = (const int*)d_in[1];
    const float* W1  = (const float*)d_in[2];
    const float* a1s = (const float*)d_in[3];
    const float* a1d = (const float*)d_in[4];
    const float* b1  = (const float*)d_in[5];
    const float* W2  = (const float*)d_in[6];
    const float* a2s = (const float*)d_in[7];
    const float* a2d = (const float*)d_in[8];
    const float* b2  = (const float*)d_in[9];
    const float* W3  = (const float*)d_in[10];
    const float* a3s = (const float*)d_in[11];
    const float* a3d = (const float*)d_in[12];
    const float* b3  = (const float*)d_in[13];
    const float* Wc  = (const float*)d_in[14];
    const float* bc  = (const float*)d_in[15];

    const int N = in_sizes[0] / 128;
    const int E = in_sizes[1] / 2;
    const int* src = ei;
    const int* dst = ei + E;
    const int nbkt = (N + BKT_NODES - 1) >> BKT_BITS;   // 196
    const int NP = nbkt * BKT_NODES;
    const int nchunks = (E + CHUNK - 1) / CHUNK;

    float* out    = (float*)d_out;
    float* out_h1 = out;
    float* out_h2 = out + (size_t)4 * N;
    float* out_h3 = out + (size_t)8 * N;
    float* out_c  = out + (size_t)10 * N;

    char* ws = (char*)d_ws;
    size_t off = 0;
    auto alloc = [&](size_t bytes) -> void* {
        void* p = ws + off;
        off = (off + bytes + 255) & ~(size_t)255;
        return p;
    };
    int*   bcnt    = (int*)  alloc(256 * 4);
    int*   bo      = (int*)  alloc(257 * 4);
    int*   gcur    = (int*)  alloc(256 * 4);
    int*   packed  = (int*)  alloc((size_t)E * 4);    // dead after lsort -> reused as planes
    int*   packed2 = (int*)  alloc((size_t)E * 4);
    float* recA    = (float*)alloc((size_t)N * 4 * 4);
    float* adA     = (float*)alloc((size_t)N * 4);
    float* recB    = (float*)alloc((size_t)N * 4 * 4);
    float* adB     = (float*)alloc((size_t)N * 4);
    float* planes  = (float*)packed;                  // SLICES*5*NP*4 = 16MB <= 25.6MB
    if (off > ws_size) return;

    const int nb = (N + 255) / 256;

    hipMemsetAsync(bcnt, 0, 256 * 4, stream);
    l1_init_kernel<<<nb, 256, 0, stream>>>(x, W1, a1s, a1d, recA, adA, N);
    // pass 1: bucket-sort by dst>>9 (staged, coalesced copy-out)
    bhist_kernel<<<nchunks, 256, 0, stream>>>(dst, bcnt, E, nbkt);
    bscan_kernel<<<1, 256, 0, stream>>>(bcnt, bo, gcur, nbkt, E);
    bscat_kernel<<<nchunks, 512, 0, stream>>>(src, dst, gcur, packed, E);
    // pass 1.5: bucket-local exact-dst sort (single block owns bucket span)
    lsort_kernel<<<nbkt, 1024, 0, stream>>>(bo, packed, packed2);

    // layer 1
    agg4_kernel<4><<<nbkt * SLICES, 256, 0, stream>>>(bo, packed2, recA, adA, planes, NP, N);
    finA_kernel<4><<<nb, 256, 0, stream>>>(planes, NP, recA, adA, b1, W2, a2s, a2d,
                                           out_h1, recB, adB, N);
    // layer 2
    agg4_kernel<4><<<nbkt * SLICES, 256, 0, stream>>>(bo, packed2, recB, adB, planes, NP, N);
    finA_kernel<2><<<nb, 256, 0, stream>>>(planes, NP, recB, adB, b2, W3, a3s, a3d,
                                           out_h2, recA, adA, N);
    // layer 3
    agg4_kernel<2><<<nbkt * SLICES, 256, 0, stream>>>(bo, packed2, recA, adA, planes, NP, N);
    finC_kernel<<<nb, 256, 0, stream>>>(planes, NP, recA, adA, b3, Wc, bc, out_h3, out_c, N);
}

// Round 16
// 331.616 us; speedup vs baseline: 1.3383x; 1.1986x over previous
//
#include <hip/hip_runtime.h>
#include <hip/hip_fp16.h>

#define NEG_SLOPE 0.2f
#define BKT_BITS 9
#define BKT_NODES 512
#define CHUNK 8192
#define SLICES 8
#define LCAP 36864               // lsort LDS stage capacity (mean 32.6K + 23 sigma)

typedef float v4f __attribute__((ext_vector_type(4)));

__device__ __forceinline__ float lrelu(float x) { return x > 0.f ? x : NEG_SLOPE * x; }

// Real hardware LDS float atomic add (emits ds_add_f32)
__device__ __forceinline__ void ldsAddF32(float* p, float v) {
    asm volatile("ds_add_f32 %0, %1" : : "v"((unsigned)(uintptr_t)p), "v"(v));
}

__device__ __forceinline__ int ntLoadI(const int* p) { return __builtin_nontemporal_load(p); }
__device__ __forceinline__ v4f ntLoadV4(const float* p) {
    return __builtin_nontemporal_load((const v4f*)p);
}
__device__ __forceinline__ float ntLoadF(const float* p) { return __builtin_nontemporal_load(p); }
__device__ __forceinline__ void ntStoreI(int* p, int v) { __builtin_nontemporal_store(v, p); }
__device__ __forceinline__ void ntStoreF(float* p, float v) { __builtin_nontemporal_store(v, p); }

union H2F { __half2 h; float f; };
__device__ __forceinline__ float2 unpackH2(float bits) {
    H2F u; u.f = bits; return __half22float2(u.h);
}
__device__ __forceinline__ float packH2(float a, float b) {
    H2F u; u.h = __float22half2_rn(make_float2(a, b)); return u.f;
}

// ---------------- Layer-1 init ----------------
__global__ void l1_init_kernel(const float* __restrict__ x,
                               const float* __restrict__ W1,
                               const float* __restrict__ a_s,
                               const float* __restrict__ a_d,
                               float* __restrict__ rec,
                               float* __restrict__ ad_,
                               int N)
{
    __shared__ float Wl[512];
    for (int i = threadIdx.x; i < 512; i += blockDim.x) Wl[i] = W1[i];
    __syncthreads();
    int n = blockIdx.x * blockDim.x + threadIdx.x;
    if (n >= N) return;
    const float* xr = x + (size_t)n * 128;
    float a0 = 0.f, a1 = 0.f, a2 = 0.f, a3 = 0.f;
#pragma unroll 8
    for (int j = 0; j < 32; ++j) {
        v4f v = ntLoadV4(xr + 4 * j);
        const float* w = &Wl[j * 16];
        a0 += v.x * w[0] + v.y * w[4] + v.z * w[8]  + v.w * w[12];
        a1 += v.x * w[1] + v.y * w[5] + v.z * w[9]  + v.w * w[13];
        a2 += v.x * w[2] + v.y * w[6] + v.z * w[10] + v.w * w[14];
        a3 += v.x * w[3] + v.y * w[7] + v.z * w[11] + v.w * w[15];
    }
    float asv = a0 * a_s[0] + a1 * a_s[1] + a2 * a_s[2] + a3 * a_s[3];
    ((float4*)rec)[n] = make_float4(packH2(a0, a1), packH2(a2, a3), asv, 0.f);
    ad_[n] = a0 * a_d[0] + a1 * a_d[1] + a2 * a_d[2] + a3 * a_d[3];
}

// ---------------- pass 1: bucket by dst >> 9 ----------------
__global__ void bhist_kernel(const int* __restrict__ dst, int* __restrict__ bcnt, int E, int nbkt)
{
    __shared__ int h[256];
    h[threadIdx.x] = 0;
    __syncthreads();
    int base = blockIdx.x * CHUNK;
    int end = min(base + CHUNK, E);
    for (int i = base + threadIdx.x; i < end; i += 256)
        atomicAdd(&h[ntLoadI(dst + i) >> BKT_BITS], 1);
    __syncthreads();
    if ((int)threadIdx.x < nbkt && h[threadIdx.x])
        atomicAdd(&bcnt[threadIdx.x], h[threadIdx.x]);
}

__global__ void bscan_kernel(const int* __restrict__ bcnt, int* __restrict__ bo,
                             int* __restrict__ gcur, int nbkt, int E)
{
    __shared__ int sh[256];
    int t = threadIdx.x;
    int v = (t < nbkt) ? bcnt[t] : 0;
    sh[t] = v;
    __syncthreads();
    for (int o = 1; o < 256; o <<= 1) {
        int u = (t >= o) ? sh[t - o] : 0;
        __syncthreads();
        sh[t] += u;
        __syncthreads();
    }
    if (t < nbkt) { int e = sh[t] - v; bo[t] = e; gcur[t] = e; }
    if (t == 0) bo[nbkt] = E;
}

// Staged bucket scatter, 512 threads: LDS-stage in bucket order, coalesced nt copy-out
__global__ void __launch_bounds__(512) bscat_kernel(const int* __restrict__ src,
                                                    const int* __restrict__ dst,
                                                    int* __restrict__ gcur,
                                                    int* __restrict__ packed,
                                                    int E)
{
    __shared__ int hist[256];
    __shared__ int lbase[256];
    __shared__ int gbase[256];
    __shared__ int lcur[256];
    __shared__ int sc[256];
    __shared__ int stage[CHUNK];
    __shared__ unsigned char sbkt[CHUNK];
    int t = threadIdx.x;
    if (t < 256) { hist[t] = 0; lcur[t] = 0; }
    __syncthreads();
    int base = blockIdx.x * CHUNK;
    int end = min(base + CHUNK, E);
    for (int i = base + t; i < end; i += 512)
        atomicAdd(&hist[ntLoadI(dst + i) >> BKT_BITS], 1);
    __syncthreads();
    int v = (t < 256) ? hist[t] : 0;
    if (t < 256) sc[t] = v;
    __syncthreads();
    for (int o = 1; o < 256; o <<= 1) {
        int u = 0;
        if (t < 256 && t >= o) u = sc[t - o];
        __syncthreads();
        if (t < 256) sc[t] += u;
        __syncthreads();
    }
    if (t < 256) {
        lbase[t] = sc[t] - v;
        if (v > 0) gbase[t] = atomicAdd(&gcur[t], v);
    }
    __syncthreads();
    for (int i = base + t; i < end; i += 512) {
        int d = ntLoadI(dst + i);
        int b = d >> BKT_BITS;
        int r = atomicAdd(&lcur[b], 1);
        int p = lbase[b] + r;
        stage[p] = ntLoadI(src + i) | ((d & (BKT_NODES - 1)) << 17);
        sbkt[p] = (unsigned char)b;
    }
    __syncthreads();
    int cnt = end - base;
    for (int i = t; i < cnt; i += 512) {
        int b = sbkt[i];
        ntStoreI(&packed[gbase[b] + (i - lbase[b])], stage[i]);
    }
}

// ---------------- pass 1.5: bucket-local exact-dst sort, LDS-staged output ----------------
// Sort the whole bucket into an LDS stage (scattered ds writes are cheap), then ONE
// coalesced full-line copy-out. Fixes R14's 3x write-amp: partial lines never touch L2.
// Fallback to scattered global stores only if a bucket exceeds LCAP (mean + 23 sigma).
__global__ void __launch_bounds__(1024) lsort_kernel(const int* __restrict__ bo,
                                                     const int* __restrict__ packed,
                                                     int* __restrict__ packed2)
{
    __shared__ int hist[BKT_NODES];
    __shared__ int sc[BKT_NODES];
    __shared__ int lcur[BKT_NODES];
    __shared__ int stage[LCAP];
    int b = blockIdx.x, t = threadIdx.x;
    int beg = bo[b], end = bo[b + 1];
    int cnt = end - beg;
    if (t < BKT_NODES) hist[t] = 0;
    __syncthreads();
    for (int i = beg + t; i < end; i += 1024)
        atomicAdd(&hist[ntLoadI(packed + i) >> 17], 1);
    __syncthreads();
    if (t < BKT_NODES) sc[t] = hist[t];
    __syncthreads();
    for (int o = 1; o < BKT_NODES; o <<= 1) {
        int u = 0;
        if (t < BKT_NODES && t >= o) u = sc[t - o];
        __syncthreads();
        if (t < BKT_NODES) sc[t] += u;
        __syncthreads();
    }
    if (t < BKT_NODES) lcur[t] = sc[t] - hist[t];   // bucket-local exclusive base
    __syncthreads();
    if (cnt <= LCAP) {
        for (int i = beg + t; i < end; i += 1024) {
            int p = ntLoadI(packed + i);
            int pos = atomicAdd(&lcur[p >> 17], 1);
            stage[pos] = p;                          // scattered ds_write (cheap)
        }
        __syncthreads();
        for (int i = t; i < cnt; i += 1024)
            ntStoreI(&packed2[beg + i], stage[i]);   // coalesced full lines
    } else {
        for (int i = beg + t; i < end; i += 1024) {  // overflow fallback (never for random)
            int p = ntLoadI(packed + i);
            int pos = atomicAdd(&lcur[p >> 17], 1);
            packed2[beg + pos] = p;
        }
    }
}

// ---------------- aggregation: register run-accumulation over dst-sorted edges ----------------
template <int F>
__global__ void __launch_bounds__(256) agg4_kernel(const int* __restrict__ bo,
                           const int* __restrict__ packed2,
                           const float* __restrict__ rec, const float* __restrict__ ad_,
                           float* __restrict__ planes, int NP, int N)
{
    constexpr int C = F + 1;
    __shared__ float acc[C * BKT_NODES];
    __shared__ float adl[BKT_NODES];
    int b  = blockIdx.x >> 3;
    int sl = blockIdx.x & 7;
    int t  = threadIdx.x;
    for (int i = t; i < C * BKT_NODES; i += 256) acc[i] = 0.f;
    int nbase = b << BKT_BITS;
    for (int i = t; i < BKT_NODES; i += 256)
        adl[i] = (nbase + i < N) ? ad_[nbase + i] : 0.f;
    __syncthreads();
    int beg = bo[b], end = bo[b + 1];
    int cnt = end - beg;
    int per = (cnt + SLICES - 1) / SLICES;
    int s0 = beg + sl * per;
    int s1 = min(s0 + per, end);
    const v4f* recf = (const v4f*)rec;
    if (s1 > s0) {
        int len = s1 - s0;
        int K = (len + 255) >> 8;          // consecutive edges per thread
        int e0 = s0 + t * K;
        int e1 = min(e0 + K, s1);
        float r0 = 0.f, r1 = 0.f, r2 = 0.f, r3 = 0.f, rw = 0.f, av = 0.f;
        int cur_ld = -1;
        auto flushRun = [&]() {
            if (cur_ld >= 0) {
                ldsAddF32(&acc[0 * BKT_NODES + cur_ld], r0);
                ldsAddF32(&acc[1 * BKT_NODES + cur_ld], r1);
                if (F == 4) {
                    ldsAddF32(&acc[2 * BKT_NODES + cur_ld], r2);
                    ldsAddF32(&acc[3 * BKT_NODES + cur_ld], r3);
                }
                ldsAddF32(&acc[F * BKT_NODES + cur_ld], rw);
            }
        };
        auto consume = [&](int p, v4f q) {
            int ld = p >> 17;
            if (ld != cur_ld) {
                flushRun();
                cur_ld = ld; av = adl[ld];
                r0 = r1 = r2 = r3 = rw = 0.f;
            }
            float w = __expf(lrelu(q.z + av));
            if (F == 4) {
                float2 a01 = unpackH2(q.x), a23 = unpackH2(q.y);
                r0 += w * a01.x; r1 += w * a01.y; r2 += w * a23.x; r3 += w * a23.y;
            } else {
                r0 += w * q.x; r1 += w * q.y;
            }
            rw += w;
        };
        for (int i = e0; i < e1; i += 4) {
            int p0 = packed2[i];
            int p1 = (i + 1 < e1) ? packed2[i + 1] : -1;
            int p2 = (i + 2 < e1) ? packed2[i + 2] : -1;
            int p3 = (i + 3 < e1) ? packed2[i + 3] : -1;
            v4f q0 = recf[p0 & 0x1FFFF];
            v4f q1 = recf[(p1 < 0 ? p0 : p1) & 0x1FFFF];
            v4f q2 = recf[(p2 < 0 ? p0 : p2) & 0x1FFFF];
            v4f q3 = recf[(p3 < 0 ? p0 : p3) & 0x1FFFF];
            consume(p0, q0);
            if (p1 >= 0) consume(p1, q1);
            if (p2 >= 0) consume(p2, q2);
            if (p3 >= 0) consume(p3, q3);
        }
        flushRun();
    }
    asm volatile("s_waitcnt lgkmcnt(0)" ::: "memory");
    __syncthreads();
    float* pl = planes + (size_t)sl * C * NP + nbase;
    for (int i = t; i < C * BKT_NODES; i += 256)
        ntStoreF(&pl[(size_t)(i >> BKT_BITS) * NP + (i & (BKT_NODES - 1))], acc[i]);
}

// ---------------- finalize layers 1,2 ----------------
template <int FO>
__global__ void finA_kernel(const float* __restrict__ planes, int NP,
                            const float* __restrict__ rec, const float* __restrict__ ad_,
                            const float* __restrict__ bias,
                            const float* __restrict__ Wn, const float* __restrict__ ans,
                            const float* __restrict__ andd,
                            float* __restrict__ out_h, float* __restrict__ recn,
                            float* __restrict__ adn_, int N)
{
    int n = blockIdx.x * blockDim.x + threadIdx.x;
    if (n >= N) return;
    float g[5] = {0.f, 0.f, 0.f, 0.f, 0.f};
#pragma unroll
    for (int sl = 0; sl < SLICES; ++sl) {
        const float* pl = planes + (size_t)sl * 5 * NP + n;
#pragma unroll
        for (int c = 0; c < 5; ++c) g[c] += ntLoadF(&pl[(size_t)c * NP]);
    }
    float4 r = ((const float4*)rec)[n];
    float2 h01 = unpackH2(r.x);
    float2 h23 = unpackH2(r.y);
    float w0 = __expf(lrelu(r.z + ad_[n]));
    float inv = 1.f / (g[4] + w0);
    float hr[4];
    hr[0] = tanhf((g[0] + w0 * h01.x) * inv + bias[0]);
    hr[1] = tanhf((g[1] + w0 * h01.y) * inv + bias[1]);
    hr[2] = tanhf((g[2] + w0 * h23.x) * inv + bias[2]);
    hr[3] = tanhf((g[3] + w0 * h23.y) * inv + bias[3]);
    ((float4*)out_h)[n] = make_float4(hr[0], hr[1], hr[2], hr[3]);
    if (FO == 4) {
        float hp[4]; float s = 0.f, d = 0.f;
#pragma unroll
        for (int q = 0; q < 4; ++q) {
            float v = hr[0] * Wn[q] + hr[1] * Wn[4 + q] + hr[2] * Wn[8 + q] + hr[3] * Wn[12 + q];
            hp[q] = v; s += v * ans[q]; d += v * andd[q];
        }
        ((float4*)recn)[n] = make_float4(packH2(hp[0], hp[1]), packH2(hp[2], hp[3]), s, 0.f);
        adn_[n] = d;
    } else {
        float hp0 = hr[0] * Wn[0] + hr[1] * Wn[2] + hr[2] * Wn[4] + hr[3] * Wn[6];
        float hp1 = hr[0] * Wn[1] + hr[1] * Wn[3] + hr[2] * Wn[5] + hr[3] * Wn[7];
        float s = hp0 * ans[0] + hp1 * ans[1];
        ((float4*)recn)[n] = make_float4(hp0, hp1, s, 0.f);
        adn_[n] = hp0 * andd[0] + hp1 * andd[1];
    }
}

// ---------------- finalize layer 3 ----------------
__global__ void finC_kernel(const float* __restrict__ planes, int NP,
                            const float* __restrict__ rec, const float* __restrict__ ad_,
                            const float* __restrict__ bias,
                            const float* __restrict__ Wc, const float* __restrict__ bc,
                            float* __restrict__ out_h, float* __restrict__ out_c, int N)
{
    int n = blockIdx.x * blockDim.x + threadIdx.x;
    if (n >= N) return;
    float g[3] = {0.f, 0.f, 0.f};
#pragma unroll
    for (int sl = 0; sl < SLICES; ++sl) {
        const float* pl = planes + (size_t)sl * 3 * NP + n;
#pragma unroll
        for (int c = 0; c < 3; ++c) g[c] += ntLoadF(&pl[(size_t)c * NP]);
    }
    float4 r = ((const float4*)rec)[n];
    float w0 = __expf(lrelu(r.z + ad_[n]));
    float inv = 1.f / (g[2] + w0);
    float hr0 = tanhf((g[0] + w0 * r.x) * inv + bias[0]);
    float hr1 = tanhf((g[1] + w0 * r.y) * inv + bias[1]);
    ((float2*)out_h)[n] = make_float2(hr0, hr1);
    float o[8];
#pragma unroll
    for (int c = 0; c < 8; ++c) o[c] = hr0 * Wc[c] + hr1 * Wc[8 + c] + bc[c];
    float4* op = (float4*)(out_c + (size_t)n * 8);
    op[0] = make_float4(o[0], o[1], o[2], o[3]);
    op[1] = make_float4(o[4], o[5], o[6], o[7]);
}

extern "C" void kernel_launch(void* const* d_in, const int* in_sizes, int n_in,
                              void* d_out, int out_size, void* d_ws, size_t ws_size,
                              hipStream_t stream)
{
    const float* x   = (const float*)d_in[0];
    const int*   ei  = (const int*)d_in[1];
    const float* W1  = (const float*)d_in[2];
    const float* a1s = (const float*)d_in[3];
    const float* a1d = (const float*)d_in[4];
    const float* b1  = (const float*)d_in[5];
    const float* W2  = (const float*)d_in[6];
    const float* a2s = (const float*)d_in[7];
    const float* a2d = (const float*)d_in[8];
    const float* b2  = (const float*)d_in[9];
    const float* W3  = (const float*)d_in[10];
    const float* a3s = (const float*)d_in[11];
    const float* a3d = (const float*)d_in[12];
    const float* b3  = (const float*)d_in[13];
    const float* Wc  = (const float*)d_in[14];
    const float* bc  = (const float*)d_in[15];

    const int N = in_sizes[0] / 128;
    const int E = in_sizes[1] / 2;
    const int* src = ei;
    const int* dst = ei + E;
    const int nbkt = (N + BKT_NODES - 1) >> BKT_BITS;   // 196
    const int NP = nbkt * BKT_NODES;
    const int nchunks = (E + CHUNK - 1) / CHUNK;

    float* out    = (float*)d_out;
    float* out_h1 = out;
    float* out_h2 = out + (size_t)4 * N;
    float* out_h3 = out + (size_t)8 * N;
    float* out_c  = out + (size_t)10 * N;

    char* ws = (char*)d_ws;
    size_t off = 0;
    auto alloc = [&](size_t bytes) -> void* {
        void* p = ws + off;
        off = (off + bytes + 255) & ~(size_t)255;
        return p;
    };
    int*   bcnt    = (int*)  alloc(256 * 4);
    int*   bo      = (int*)  alloc(257 * 4);
    int*   gcur    = (int*)  alloc(256 * 4);
    int*   packed  = (int*)  alloc((size_t)E * 4);    // dead after lsort -> reused as planes
    int*   packed2 = (int*)  alloc((size_t)E * 4);
    float* recA    = (float*)alloc((size_t)N * 4 * 4);
    float* adA     = (float*)alloc((size_t)N * 4);
    float* recB    = (float*)alloc((size_t)N * 4 * 4);
    float* adB     = (float*)alloc((size_t)N * 4);
    float* planes  = (float*)packed;                  // SLICES*5*NP*4 = 16MB <= 25.6MB
    if (off > ws_size) return;

    const int nb = (N + 255) / 256;

    hipMemsetAsync(bcnt, 0, 256 * 4, stream);
    l1_init_kernel<<<nb, 256, 0, stream>>>(x, W1, a1s, a1d, recA, adA, N);
    // pass 1: bucket-sort by dst>>9 (staged, coalesced copy-out)
    bhist_kernel<<<nchunks, 256, 0, stream>>>(dst, bcnt, E, nbkt);
    bscan_kernel<<<1, 256, 0, stream>>>(bcnt, bo, gcur, nbkt, E);
    bscat_kernel<<<nchunks, 512, 0, stream>>>(src, dst, gcur, packed, E);
    // pass 1.5: bucket-local exact-dst sort (LDS-staged, coalesced copy-out)
    lsort_kernel<<<nbkt, 1024, 0, stream>>>(bo, packed, packed2);

    // layer 1
    agg4_kernel<4><<<nbkt * SLICES, 256, 0, stream>>>(bo, packed2, recA, adA, planes, NP, N);
    finA_kernel<4><<<nb, 256, 0, stream>>>(planes, NP, recA, adA, b1, W2, a2s, a2d,
                                           out_h1, recB, adB, N);
    // layer 2
    agg4_kernel<4><<<nbkt * SLICES, 256, 0, stream>>>(bo, packed2, recB, adB, planes, NP, N);
    finA_kernel<2><<<nb, 256, 0, stream>>>(planes, NP, recB, adB, b2, W3, a3s, a3d,
                                           out_h2, recA, adA, N);
    // layer 3
    agg4_kernel<2><<<nbkt * SLICES, 256, 0, stream>>>(bo, packed2, recA, adA, planes, NP, N);
    finC_kernel<<<nb, 256, 0, stream>>>(planes, NP, recA, adA, b3, Wc, bc, out_h3, out_c, N);
}